// Round 13
// baseline (923.489 us; speedup 1.0000x reference)
//
#include <hip/hip_runtime.h>

#define BB   2
#define LL   2048
#define DD   256
#define NH   8
#define MM   (BB*LL)
#define NLAYERS 8
#define MMDD ((size_t)MM*DD)

typedef unsigned short ushort_t;
typedef __attribute__((ext_vector_type(8))) short  short8;
typedef __attribute__((ext_vector_type(4))) float  f32x4;
typedef __attribute__((ext_vector_type(4))) unsigned int u32x4;
typedef __attribute__((ext_vector_type(2))) unsigned int u32x2;

#define CSC 0.2550500394f   /* 32^-0.5 * log2(e), folded into Q */

#define WAITV0 asm volatile("s_waitcnt vmcnt(0)" ::: "memory")
#define WAITV2 asm volatile("s_waitcnt vmcnt(2)" ::: "memory")
#define WAITV4 asm volatile("s_waitcnt vmcnt(4)" ::: "memory")
#define WAITV6 asm volatile("s_waitcnt vmcnt(6)" ::: "memory")
#define WAITLG asm volatile("s_waitcnt lgkmcnt(0)" ::: "memory")
#define BAR()  __builtin_amdgcn_s_barrier()
#define SCHED0 __builtin_amdgcn_sched_barrier(0)

__device__ __forceinline__ f32x4 mfma16(short8 a, short8 b, f32x4 c) {
    return __builtin_amdgcn_mfma_f32_16x16x32_bf16(a, b, c, 0, 0, 0);
}
__device__ __forceinline__ unsigned cvtpk(float lo, float hi) {
    unsigned r;
    asm volatile("v_cvt_pk_bf16_f32 %0, %1, %2" : "=v"(r) : "v"(lo), "v"(hi));
    return r;
}
__device__ __forceinline__ void pl32(unsigned &a, unsigned &b) {
    asm volatile("v_permlane32_swap_b32 %0, %1" : "+v"(a), "+v"(b));
}
__device__ __forceinline__ float bf2f(unsigned short h) {
    return __builtin_bit_cast(float, ((unsigned)h) << 16);
}
__device__ __forceinline__ void gll16(const void* gsrc, void* ldst) {
    __builtin_amdgcn_global_load_lds(
        (const __attribute__((address_space(1))) unsigned int*)gsrc,
        (__attribute__((address_space(3))) unsigned int*)ldst, 16, 0, 0);
}

// K tile image (per zh, per 64-key tile t): off = t*2048 + (dh>>3)*512 + kk*8 + (dh&7)
// V tile image: off = t*2048 + dh*64 + (c ^ (dh&7))*8 + u; chunk c holds permuted
//   keys pk(c&3, e) = 16((c&3)>>1)+4((c&3)&1)+8(e>>2)+(e&3); key = 32(c>>2)+pk.

// ---------------------------------------------------------------------------
// Fused setup: F/Fb init (0-1023), weight conv (1024-2047), rope table (2048+)
// ---------------------------------------------------------------------------
__global__ __launch_bounds__(256) void setup(const float* __restrict__ f0,
                                             const float* __restrict__ f1,
                                             const float* __restrict__ Wq,
                                             const float* __restrict__ Wk,
                                             const float* __restrict__ Wv,
                                             const float* __restrict__ Wo,
                                             float* __restrict__ F,
                                             ushort_t* __restrict__ Fb,
                                             ushort_t* __restrict__ Wb,
                                             float* __restrict__ tab) {
    int b = blockIdx.x, t = threadIdx.x;
    if (b < 1024) {
        int i = b * 256 + t;
        const float* src = (i < 131072) ? f0 : f1;
        int loc = i & 131071;
        const f32x4* p = (const f32x4*)(src + (size_t)loc * 8);
        f32x4 a = p[0], bb = p[1];
        *(f32x4*)&F[(size_t)i * 8]     = a;
        *(f32x4*)&F[(size_t)i * 8 + 4] = bb;
        u32x4 o = {cvtpk(a.x, a.y), cvtpk(a.z, a.w), cvtpk(bb.x, bb.y), cvtpk(bb.z, bb.w)};
        *(u32x4*)&Fb[(size_t)i * 8] = o;
    } else if (b < 2048) {
        int i = (b - 1024) * 256 + t;
        int reg = i >> 16, loc = i & 65535;
        const float* src = reg == 0 ? Wq : reg == 1 ? Wk : reg == 2 ? Wv : Wo;
        const f32x4* p = (const f32x4*)(src + (size_t)loc * 8);
        f32x4 x = p[0], y = p[1];
        u32x4 o = {cvtpk(x.x, x.y), cvtpk(x.z, x.w), cvtpk(y.x, y.y), cvtpk(y.z, y.w)};
        *(u32x4*)&Wb[(size_t)reg * 524288 + (size_t)loc * 8] = o;
    } else {
        int idx = (b - 2048) * 256 + t;
        int p = idx >> 7, j = idx & 127;
        float inv = __expf(-((float)j / 128.f) * 9.210340371976184f);
        float s, c;
        sincosf((float)p * inv, &s, &c);
        tab[(size_t)p * 256 + j]       = c;
        tab[(size_t)p * 256 + 128 + j] = s;
    }
}

// ---------------------------------------------------------------------------
// gemmQK body: self Q/K projection with fused RoPE, on a shared LDS arena.
// Uses lds[0..24575]: X 2x4096 @0, WL 2x4096 @8192, WH 2x4096 @16384.
// ---------------------------------------------------------------------------
__device__ __forceinline__ void gemmQK_body(int f, ushort_t* lds,
                                            const ushort_t* __restrict__ X,
                                            const ushort_t* __restrict__ WQ,
                                            const ushort_t* __restrict__ WK,
                                            ushort_t* __restrict__ DQ,
                                            ushort_t* __restrict__ KT,
                                            const float* __restrict__ tab) {
    const int tid = threadIdx.x, ln = tid & 63, w = tid >> 6;
    const int xcd = f & 7, u = f >> 3;
    const int bx = u & 3, byg = u >> 2;
    const int mat = bx >> 1, cg = bx & 1;
    const int by = xcd * 16 + byg;
    const int m0 = by * 64, n0 = cg * 64;
    const ushort_t* W = mat ? WK : WQ;

    auto stage = [&](int c, int buf) {
#pragma unroll
        for (int i = 0; i < 2; i++) {
            int sl = (w * 2 + i) * 64 + ln;
            int r = sl >> 3, x = sl & 7;
            int col = c * 64 + ((x ^ (r & 7)) << 3);
            gll16(X + (size_t)(m0 + r) * 256 + col,       &lds[buf * 4096 + (w * 2 + i) * 512]);
            gll16(W + (size_t)(n0 + r) * 256 + col,       &lds[8192 + buf * 4096 + (w * 2 + i) * 512]);
            gll16(W + (size_t)(n0 + 128 + r) * 256 + col, &lds[16384 + buf * 4096 + (w * 2 + i) * 512]);
        }
    };

    const int ql = ln & 15, gq = ln >> 4;
    const int wm = w >> 1, wn = w & 1;
    f32x4 z4 = {0.f, 0.f, 0.f, 0.f};
    f32x4 accL[2][2] = {{z4, z4}, {z4, z4}};
    f32x4 accH[2][2] = {{z4, z4}, {z4, z4}};

    stage(0, 0);
    stage(1, 1);
#pragma unroll
    for (int c = 0; c < 4; c++) {
        if (c < 3) { WAITV6; } else { WAITV0; }
        BAR(); SCHED0;
        const ushort_t* XL = &lds[(c & 1) * 4096];
        const ushort_t* WL = &lds[8192 + (c & 1) * 4096];
        const ushort_t* WH = &lds[16384 + (c & 1) * 4096];
        __builtin_amdgcn_s_setprio(1);
#pragma unroll
        for (int ks = 0; ks < 2; ks++) {
            int cc = ks * 4 + gq;
            int r0 = 32 * wm + ql, r1 = r0 + 16;
            int nr0 = 32 * wn + ql, nr1 = nr0 + 16;
            short8 a0 = *(const short8*)&XL[(r0 * 8 + (cc ^ (r0 & 7))) * 8];
            short8 a1 = *(const short8*)&XL[(r1 * 8 + (cc ^ (r1 & 7))) * 8];
            short8 l0 = *(const short8*)&WL[(nr0 * 8 + (cc ^ (nr0 & 7))) * 8];
            short8 l1 = *(const short8*)&WL[(nr1 * 8 + (cc ^ (nr1 & 7))) * 8];
            short8 h0 = *(const short8*)&WH[(nr0 * 8 + (cc ^ (nr0 & 7))) * 8];
            short8 h1 = *(const short8*)&WH[(nr1 * 8 + (cc ^ (nr1 & 7))) * 8];
            accL[0][0] = mfma16(a0, l0, accL[0][0]);
            accL[0][1] = mfma16(a0, l1, accL[0][1]);
            accL[1][0] = mfma16(a1, l0, accL[1][0]);
            accL[1][1] = mfma16(a1, l1, accL[1][1]);
            accH[0][0] = mfma16(a0, h0, accH[0][0]);
            accH[0][1] = mfma16(a0, h1, accH[0][1]);
            accH[1][0] = mfma16(a1, h0, accH[1][0]);
            accH[1][1] = mfma16(a1, h1, accH[1][1]);
        }
        __builtin_amdgcn_s_setprio(0);
        BAR();
        if (c + 2 < 4) stage(c + 2, c & 1);
    }

#pragma unroll
    for (int mf = 0; mf < 2; mf++)
#pragma unroll
        for (int nf = 0; nf < 2; nf++)
#pragma unroll
            for (int r = 0; r < 4; r++) {
                int mg = m0 + 32 * wm + 16 * mf + gq * 4 + r;
                int jl = n0 + 32 * wn + 16 * nf + ql;
                int pos = mg & (LL - 1);
                float a = accL[mf][nf][r], b = accH[mf][nf][r];
                float c = tab[(size_t)pos * 256 + jl];
                float s = tab[(size_t)pos * 256 + 128 + jl];
                float o1 = a * c - b * s;
                float o2 = b * c + a * s;
                if (mat == 0) {
                    o1 *= CSC; o2 *= CSC;
                    DQ[(size_t)mg * 256 + jl]       = (ushort_t)cvtpk(o1, o1);
                    DQ[(size_t)mg * 256 + jl + 128] = (ushort_t)cvtpk(o2, o2);
                } else {
                    int z = mg >> 11, key = mg & 2047;
                    int tt = key >> 6, kk = key & 63;
                    int dh = jl & 31, hA = jl >> 5;
                    size_t base = (size_t)tt * 2048 + (size_t)(dh >> 3) * 512
                                + (size_t)kk * 8 + (dh & 7);
                    KT[(size_t)(z * 8 + hA) * 65536 + base]     = (ushort_t)cvtpk(o1, o1);
                    KT[(size_t)(z * 8 + hA + 4) * 65536 + base] = (ushort_t)cvtpk(o2, o2);
                }
            }
}

// ---------------------------------------------------------------------------
// gemm5 body (3-buffer pipelined, shared LDS arena: X 3x4096 @0, W 3x4096
// @12288). modes: 2 bf16 row | 3 V tile image | 4 bf16*CSC row | 5 K tile
// ---------------------------------------------------------------------------
template<int NQ, int NK, int NV, int QMODE, int KMODE, int NTY>
__device__ __forceinline__ void gemm5_body(int f, ushort_t* lds,
                                           const ushort_t* __restrict__ X,
                                           const ushort_t* __restrict__ WQ,
                                           const ushort_t* __restrict__ WK,
                                           const ushort_t* __restrict__ WV,
                                           ushort_t* __restrict__ DQ,
                                           ushort_t* __restrict__ DK,
                                           ushort_t* __restrict__ DVT) {
    constexpr int NTX = NQ + NK + NV;
    const int tid = threadIdx.x, ln = tid & 63, w = tid >> 6;
    const int xcd = f & 7, s = f >> 3;
    const int bx = s % NTX, byg = s / NTX;
    const int by = xcd * (NTY / 8) + byg;
    const int m0 = by * 64;

    const ushort_t* W; ushort_t* DH; int n0, mode;
    if (NQ && bx < NQ)           { W = WQ; DH = DQ;  mode = QMODE; n0 = bx * 64; }
    else if (NK && bx < NQ + NK) { W = WK; DH = DK;  mode = KMODE; n0 = (bx - NQ) * 64; }
    else                         { W = WV; DH = DVT; mode = 3; n0 = (bx - NQ - NK) * 64; }

    auto stage = [&](int c, int buf) {
#pragma unroll
        for (int i = 0; i < 2; i++) {
            int sl = (w * 2 + i) * 64 + ln;
            int r = sl >> 3, x = sl & 7;
            int col = c * 64 + ((x ^ (r & 7)) << 3);
            gll16(X + (size_t)(m0 + r) * 256 + col, &lds[buf * 4096 + (w * 2 + i) * 512]);
            gll16(W + (size_t)(n0 + r) * 256 + col, &lds[12288 + buf * 4096 + (w * 2 + i) * 512]);
        }
    };

    const int ql = ln & 15, gq = ln >> 4;
    const int wm = w >> 1, wn = w & 1;
    f32x4 z4 = {0.f, 0.f, 0.f, 0.f};
    f32x4 acc[2][2] = {{z4, z4}, {z4, z4}};

    stage(0, 0);
    stage(1, 1);
#pragma unroll
    for (int c = 0; c < 4; c++) {
        if (c < 3) { WAITV4; } else { WAITV0; }
        BAR(); SCHED0;
        if (c + 2 < 4) stage(c + 2, (c + 2) % 3);
        const ushort_t* XL = &lds[(c % 3) * 4096];
        const ushort_t* WL = &lds[12288 + (c % 3) * 4096];
        __builtin_amdgcn_s_setprio(1);
#pragma unroll
        for (int ks = 0; ks < 2; ks++) {
            int cc = ks * 4 + gq;
            int r0 = 32 * wm + ql, r1 = r0 + 16;
            int nr0 = 32 * wn + ql, nr1 = nr0 + 16;
            short8 a0 = *(const short8*)&XL[(r0 * 8 + (cc ^ (r0 & 7))) * 8];
            short8 a1 = *(const short8*)&XL[(r1 * 8 + (cc ^ (r1 & 7))) * 8];
            short8 b0 = *(const short8*)&WL[(nr0 * 8 + (cc ^ (nr0 & 7))) * 8];
            short8 b1 = *(const short8*)&WL[(nr1 * 8 + (cc ^ (nr1 & 7))) * 8];
            acc[0][0] = mfma16(a0, b0, acc[0][0]);
            acc[0][1] = mfma16(a0, b1, acc[0][1]);
            acc[1][0] = mfma16(a1, b0, acc[1][0]);
            acc[1][1] = mfma16(a1, b1, acc[1][1]);
        }
        __builtin_amdgcn_s_setprio(0);
    }

    if (mode == 3) {
        float* scr = (float*)lds;
        __syncthreads();
#pragma unroll
        for (int mf = 0; mf < 2; mf++)
#pragma unroll
            for (int nf = 0; nf < 2; nf++)
#pragma unroll
                for (int r = 0; r < 4; r++) {
                    int nloc = 32 * wn + 16 * nf + ql;
                    int mloc = 32 * wm + 16 * mf + 4 * gq + r;
                    scr[nloc * 65 + mloc] = acc[mf][nf][r];
                }
        __syncthreads();
        int nloc = tid >> 2, mc = (tid & 3) * 16;
        int ng = n0 + nloc, hh = ng >> 5, dh = ng & 31;
        int mg = m0 + mc;
        int z = mg >> 11, key = mg & 2047;
        int tt = key >> 6;
        int ks = (mc >> 5) & 1, J = (mc >> 4) & 1;
        int cA = 4 * ks + 2 * J, cB = cA + 1;
        int swz = dh & 7;
        const float* sc = &scr[nloc * 65 + mc];
        u32x2 q0 = {cvtpk(sc[0], sc[1]),   cvtpk(sc[2], sc[3])};
        u32x2 q1 = {cvtpk(sc[4], sc[5]),   cvtpk(sc[6], sc[7])};
        u32x2 q2 = {cvtpk(sc[8], sc[9]),   cvtpk(sc[10], sc[11])};
        u32x2 q3 = {cvtpk(sc[12], sc[13]), cvtpk(sc[14], sc[15])};
        ushort_t* base = &DVT[(size_t)(z * 8 + hh) * 65536 + (size_t)tt * 2048 + dh * 64];
        *(u32x2*)&base[(cA ^ swz) * 8]     = q0;
        *(u32x2*)&base[(cB ^ swz) * 8]     = q1;
        *(u32x2*)&base[(cA ^ swz) * 8 + 4] = q2;
        *(u32x2*)&base[(cB ^ swz) * 8 + 4] = q3;
    } else {
#pragma unroll
        for (int mf = 0; mf < 2; mf++)
#pragma unroll
            for (int nf = 0; nf < 2; nf++)
#pragma unroll
                for (int r = 0; r < 4; r++) {
                    int mg = m0 + 32 * wm + 16 * mf + gq * 4 + r;
                    int ng = n0 + 32 * wn + 16 * nf + ql;
                    float v = acc[mf][nf][r];
                    if (mode == 2) {
                        DH[(size_t)mg * 256 + ng] = (ushort_t)cvtpk(v, v);
                    } else if (mode == 5) {
                        int zh = (mg >> 11) * 8 + (ng >> 5);
                        size_t off = (size_t)zh * 65536
                                   + (size_t)((mg & 2047) >> 6) * 2048
                                   + (size_t)((ng & 31) >> 3) * 512
                                   + (size_t)(mg & 63) * 8 + (ng & 7);
                        DH[off] = (ushort_t)cvtpk(v, v);
                    } else {
                        float vs = v * CSC;
                        DH[(size_t)mg * 256 + ng] = (ushort_t)cvtpk(vs, vs);
                    }
                }
    }
}

// ---------------------------------------------------------------------------
// Fused dispatches
// ---------------------------------------------------------------------------
__global__ __launch_bounds__(256) void selfQKV(const ushort_t* __restrict__ Fb,
                                               const ushort_t* __restrict__ wq,
                                               const ushort_t* __restrict__ wk,
                                               const ushort_t* __restrict__ wv,
                                               ushort_t* __restrict__ Qb,
                                               ushort_t* __restrict__ Khb,
                                               ushort_t* __restrict__ Vhb,
                                               const float* __restrict__ tab) {
    __shared__ ushort_t lds[24576];
    int f = blockIdx.x;
    if (f < 512)
        gemmQK_body(f, lds, Fb, wq, wk, Qb, Khb, tab);
    else
        gemm5_body<0, 0, 4, 0, 0, 128>(f - 512, lds, Fb, nullptr, nullptr, wv,
                                       nullptr, nullptr, Vhb);
}

__global__ __launch_bounds__(256) void crossQKV0(const ushort_t* __restrict__ Fb,
                                                 const ushort_t* __restrict__ wq,
                                                 const ushort_t* __restrict__ sb,
                                                 const ushort_t* __restrict__ wk,
                                                 const ushort_t* __restrict__ wv,
                                                 ushort_t* __restrict__ Qb,
                                                 ushort_t* __restrict__ Khb,
                                                 ushort_t* __restrict__ Vhb) {
    __shared__ ushort_t lds[24576];
    int f = blockIdx.x;
    if (f < 512)
        gemm5_body<4, 0, 0, 4, 0, 128>(f, lds, Fb, wq, nullptr, nullptr,
                                       Qb, nullptr, nullptr);
    else
        gemm5_body<0, 4, 4, 0, 5, 64>(f - 512, lds, sb, nullptr, wk, wv,
                                      nullptr, Khb, Vhb);
}

__global__ __launch_bounds__(256) void gemmKV(const ushort_t* __restrict__ sb,
                                              const ushort_t* __restrict__ wk,
                                              const ushort_t* __restrict__ wv,
                                              ushort_t* __restrict__ Khb,
                                              ushort_t* __restrict__ Vhb) {
    __shared__ ushort_t lds[24576];
    gemm5_body<0, 4, 4, 0, 5, 64>(blockIdx.x, lds, sb, nullptr, wk, wv,
                                  nullptr, Khb, Vhb);
}

// ---------------------------------------------------------------------------
// Out-projection GEMM with fused split-combine; bf16 partials.
// ---------------------------------------------------------------------------
template<int SPLIT, int NTY>
__global__ __launch_bounds__(256) void gemmO(const ushort_t* __restrict__ Opb,
                                             const float* __restrict__ Lp,
                                             const ushort_t* __restrict__ W,
                                             const float* __restrict__ Res,
                                             float* __restrict__ OutF,
                                             ushort_t* __restrict__ OutH,
                                             int mrows) {
    __shared__ ushort_t Xf[64 * 256];
    __shared__ ushort_t Wpb[3][4096];
    const int tid = threadIdx.x, ln = tid & 63, w = tid >> 6;
    const int f = blockIdx.x;
    const int xcd = f & 7, s = f >> 3;
    const int bx = s & 3, byg = s >> 2;
    const int by = xcd * (NTY / 8) + byg;
    const int m0 = by * 64, n0 = bx * 64;

    auto stageW = [&](int c, int buf) {
#pragma unroll
        for (int i = 0; i < 2; i++) {
            int sl = (w * 2 + i) * 64 + ln;
            int r = sl >> 3, x = sl & 7;
            int col = c * 64 + ((x ^ (r & 7)) << 3);
            gll16(W + (size_t)(n0 + r) * 256 + col, &Wpb[buf][(w * 2 + i) * 512]);
        }
    };
    stageW(0, 0);
    stageW(1, 1);

    const int xr = tid >> 2, q = tid & 3, hb = q >> 1;
    float inv[4];
#pragma unroll
    for (int hh = 0; hh < 4; hh++) {
        float l = 0.f;
#pragma unroll
        for (int sp = 0; sp < SPLIT; sp++)
            l += Lp[(size_t)sp * mrows * 8 + (size_t)(m0 + xr) * 8 + 2 * hh + hb];
        inv[hh] = 1.f / l;
    }
#pragma unroll
    for (int p = 0; p < 4; p++) {
        int col = q * 16 + 64 * p;
        f32x4 a0 = {0.f,0.f,0.f,0.f}, a1 = a0, a2 = a0, a3 = a0;
#pragma unroll
        for (int sp = 0; sp < SPLIT; sp++) {
            const ushort_t* src = &Opb[((size_t)sp * mrows + m0 + xr) * 256 + col];
            u32x4 v0 = *(const u32x4*)&src[0];
            u32x4 v1 = *(const u32x4*)&src[8];
            f32x4 b0 = {bf2f(v0.x & 0xffff), bf2f(v0.x >> 16),
                        bf2f(v0.y & 0xffff), bf2f(v0.y >> 16)};
            f32x4 b1 = {bf2f(v0.z & 0xffff), bf2f(v0.z >> 16),
                        bf2f(v0.w & 0xffff), bf2f(v0.w >> 16)};
            f32x4 b2 = {bf2f(v1.x & 0xffff), bf2f(v1.x >> 16),
                        bf2f(v1.y & 0xffff), bf2f(v1.y >> 16)};
            f32x4 b3 = {bf2f(v1.z & 0xffff), bf2f(v1.z >> 16),
                        bf2f(v1.w & 0xffff), bf2f(v1.w >> 16)};
            a0 += b0; a1 += b1; a2 += b2; a3 += b3;
        }
        float iv = inv[p];
        a0 *= iv; a1 *= iv; a2 *= iv; a3 *= iv;
        u32x4 w0 = {cvtpk(a0.x, a0.y), cvtpk(a0.z, a0.w),
                    cvtpk(a1.x, a1.y), cvtpk(a1.z, a1.w)};
        u32x4 w1 = {cvtpk(a2.x, a2.y), cvtpk(a2.z, a2.w),
                    cvtpk(a3.x, a3.y), cvtpk(a3.z, a3.w)};
        int xc0 = q * 2;
        *(u32x4*)&Xf[xr * 256 + p * 64 + ((xc0)     ^ (xr & 7)) * 8] = w0;
        *(u32x4*)&Xf[xr * 256 + p * 64 + ((xc0 + 1) ^ (xr & 7)) * 8] = w1;
    }
    WAITLG;
    BAR(); SCHED0;

    const int ql = ln & 15, gq = ln >> 4;
    const int wm = w >> 1, wn = w & 1;
    f32x4 z4 = {0.f, 0.f, 0.f, 0.f};
    f32x4 acc[2][2] = {{z4, z4}, {z4, z4}};
#pragma unroll
    for (int c = 0; c < 4; c++) {
        if (c < 3) { WAITV2; } else { WAITV0; }
        BAR(); SCHED0;
        if (c + 2 < 4) stageW(c + 2, (c + 2) % 3);
        const ushort_t* WL = Wpb[c % 3];
        __builtin_amdgcn_s_setprio(1);
#pragma unroll
        for (int ks = 0; ks < 2; ks++) {
            int cc = ks * 4 + gq;
            int r0 = 32 * wm + ql, r1 = r0 + 16;
            int nr0 = 32 * wn + ql, nr1 = nr0 + 16;
            short8 a0 = *(const short8*)&Xf[r0 * 256 + c * 64 + (cc ^ (r0 & 7)) * 8];
            short8 a1 = *(const short8*)&Xf[r1 * 256 + c * 64 + (cc ^ (r1 & 7)) * 8];
            short8 b0 = *(const short8*)&WL[(nr0 * 8 + (cc ^ (nr0 & 7))) * 8];
            short8 b1 = *(const short8*)&WL[(nr1 * 8 + (cc ^ (nr1 & 7))) * 8];
            acc[0][0] = mfma16(a0, b0, acc[0][0]);
            acc[0][1] = mfma16(a0, b1, acc[0][1]);
            acc[1][0] = mfma16(a1, b0, acc[1][0]);
            acc[1][1] = mfma16(a1, b1, acc[1][1]);
        }
        __builtin_amdgcn_s_setprio(0);
    }

#pragma unroll
    for (int mf = 0; mf < 2; mf++)
#pragma unroll
        for (int nf = 0; nf < 2; nf++)
#pragma unroll
            for (int r = 0; r < 4; r++) {
                int mg = m0 + 32 * wm + 16 * mf + gq * 4 + r;
                int ng = n0 + 32 * wn + 16 * nf + ql;
                size_t idx = (size_t)mg * 256 + ng;
                float o = Res[idx] + acc[mf][nf][r];
                OutF[idx] = o;
                OutH[idx] = (ushort_t)cvtpk(o, o);
            }
}

// ---------------------------------------------------------------------------
// Flash MFMA attention v11: 2-buffer 16KB LDS (8 blocks/CU), depth-1
// prefetch (WAITV0 + 1 barrier/tile; safe: buf (t+1)&1 was last read at
// t-1, all waves passed tile-t barrier), in-register P via permlane32,
// VALU row-sum l (frees lacc/ones VGPRs). launch_bounds(256,8).
// grid = 8 xcd * 16 qb * (zcnt*SPLIT).
// ---------------------------------------------------------------------------
template<int SPLIT>
__global__ __launch_bounds__(256, 8) void attn11(const ushort_t* __restrict__ Q,
                                                 const ushort_t* __restrict__ K,
                                                 const ushort_t* __restrict__ Vt,
                                                 ushort_t* __restrict__ Opb,
                                                 float* __restrict__ Lp, int mrows) {
    constexpr int NT = 32 / SPLIT;
    __shared__ ushort_t K_lds[2][2048];
    __shared__ ushort_t V_lds[2][2048];

    const int tid = threadIdx.x, ln = tid & 63, w = tid >> 6;
    const int ql = ln & 15, gq = ln >> 4;
    const int f = blockIdx.x;
    const int xcd = f & 7, slot = f >> 3;
    const int qb = slot & 15, gg = slot >> 4;
    const int h = xcd;
    const int zz = gg / SPLIT, sp = gg % SPLIT;
    const int t0 = sp * NT;
    const int q0 = qb * 128 + w * 32;
    const size_t rb = (size_t)zz * 2048;
    const int zh = zz * 8 + h;

    short8 qfA = *(const short8*)&Q[(rb + q0 + ql) * 256 + h * 32 + gq * 8];
    short8 qfB = *(const short8*)&Q[(rb + q0 + 16 + ql) * 256 + h * 32 + gq * 8];

    const ushort_t* kt = K  + (size_t)zh * 65536 + (size_t)t0 * 2048 + tid * 8;
    const ushort_t* vt = Vt + (size_t)zh * 65536 + (size_t)t0 * 2048 + tid * 8;

    gll16(kt, &K_lds[0][w * 512]);
    gll16(vt, &V_lds[0][w * 512]);

    f32x4 z4 = {0.f, 0.f, 0.f, 0.f};
    f32x4 o0A = z4, o1A = z4, o0B = z4, o1B = z4;
    float lA = 0.f, lB = 0.f;

    for (int t = 0; t < NT; t++) {
        WAITV0;
        BAR(); SCHED0;
        if (t + 1 < NT) {
            gll16(kt + (size_t)(t + 1) * 2048, &K_lds[(t + 1) & 1][w * 512]);
            gll16(vt + (size_t)(t + 1) * 2048, &V_lds[(t + 1) & 1][w * 512]);
        }
        const ushort_t* KL = K_lds[t & 1];
        const ushort_t* VL = V_lds[t & 1];

        f32x4 stA[4], stB[4];
        __builtin_amdgcn_s_setprio(1);
#pragma unroll
        for (int j = 0; j < 4; j++) {
            short8 kf = *(const short8*)&KL[(gq * 64 + 16 * j + ql) * 8];
            stA[j] = mfma16(kf, qfA, z4);
            stB[j] = mfma16(kf, qfB, z4);
        }
        __builtin_amdgcn_s_setprio(0);
#pragma unroll
        for (int j = 0; j < 4; j++)
#pragma unroll
            for (int r = 0; r < 4; r++) {
                stA[j][r] = __builtin_amdgcn_exp2f(stA[j][r]);
                stB[j][r] = __builtin_amdgcn_exp2f(stB[j][r]);
            }
        // VALU row-sum of P (this lane's 16 keys per half); cross-gq at end
        float sA = 0.f, sB = 0.f;
#pragma unroll
        for (int j = 0; j < 4; j++)
#pragma unroll
            for (int r = 0; r < 4; r++) {
                sA += stA[j][r];
                sB += stB[j][r];
            }
        lA += sA;
        lB += sB;

        unsigned aLo[4], aHi[4], bLo[4], bHi[4];
#pragma unroll
        for (int j = 0; j < 4; j++) {
            aLo[j] = cvtpk(stA[j][0], stA[j][1]);
            aHi[j] = cvtpk(stA[j][2], stA[j][3]);
            bLo[j] = cvtpk(stB[j][0], stB[j][1]);
            bHi[j] = cvtpk(stB[j][2], stB[j][3]);
        }
        pl32(aLo[0], aLo[1]); pl32(aHi[0], aHi[1]);
        pl32(aLo[2], aLo[3]); pl32(aHi[2], aHi[3]);
        pl32(bLo[0], bLo[1]); pl32(bHi[0], bHi[1]);
        pl32(bLo[2], bLo[3]); pl32(bHi[2], bHi[3]);
        u32x4 fA0 = {aLo[0], aHi[0], aLo[1], aHi[1]};
        u32x4 fA1 = {aLo[2], aHi[2], aLo[3], aHi[3]};
        u32x4 fB0 = {bLo[0], bHi[0], bLo[1], bHi[1]};
        u32x4 fB1 = {bLo[2], bHi[2], bLo[3], bHi[3]};
        short8 pfA0 = __builtin_bit_cast(short8, fA0);
        short8 pfA1 = __builtin_bit_cast(short8, fA1);
        short8 pfB0 = __builtin_bit_cast(short8, fB0);
        short8 pfB1 = __builtin_bit_cast(short8, fB1);

        __builtin_amdgcn_s_setprio(1);
#pragma unroll
        for (int ks = 0; ks < 2; ks++) {
            int sw = (4 * ks + gq) ^ (ql & 7);
            short8 vf0 = *(const short8*)&VL[(ql * 8 + sw) * 8];
            short8 vf1 = *(const short8*)&VL[((16 + ql) * 8 + sw) * 8];
            short8 pA = ks ? pfA1 : pfA0;
            short8 pB = ks ? pfB1 : pfB0;
            o0A = mfma16(vf0, pA, o0A);
            o1A = mfma16(vf1, pA, o1A);
            o0B = mfma16(vf0, pB, o0B);
            o1B = mfma16(vf1, pB, o1B);
        }
        __builtin_amdgcn_s_setprio(0);
    }

    lA += __shfl_xor(lA, 16); lA += __shfl_xor(lA, 32);
    lB += __shfl_xor(lB, 16); lB += __shfl_xor(lB, 32);

    size_t rowA = rb + q0 + ql, rowB = rowA + 16;
    ushort_t* obA = Opb + ((size_t)sp * mrows + rowA) * 256 + h * 32;
    ushort_t* obB = Opb + ((size_t)sp * mrows + rowB) * 256 + h * 32;
    u32x2 wA0 = {cvtpk(o0A.x, o0A.y), cvtpk(o0A.z, o0A.w)};
    u32x2 wA1 = {cvtpk(o1A.x, o1A.y), cvtpk(o1A.z, o1A.w)};
    u32x2 wB0 = {cvtpk(o0B.x, o0B.y), cvtpk(o0B.z, o0B.w)};
    u32x2 wB1 = {cvtpk(o1B.x, o1B.y), cvtpk(o1B.z, o1B.w)};
    *(u32x2*)&obA[gq * 4]      = wA0;
    *(u32x2*)&obA[16 + gq * 4] = wA1;
    *(u32x2*)&obB[gq * 4]      = wB0;
    *(u32x2*)&obB[16 + gq * 4] = wB1;
    if (gq == 0) {
        Lp[(size_t)sp * mrows * 8 + rowA * 8 + h] = lA;
        Lp[(size_t)sp * mrows * 8 + rowB * 8 + h] = lB;
    }
}

// ---------------------------------------------------------------------------
extern "C" void kernel_launch(void* const* d_in, const int* in_sizes, int n_in,
                              void* d_out, int out_size, void* d_ws, size_t ws_size,
                              hipStream_t stream) {
    const float* f0_in = (const float*)d_in[0];
    const float* f1_in = (const float*)d_in[1];
    const float* Wq = (const float*)d_in[2];
    const float* Wk = (const float*)d_in[3];
    const float* Wv = (const float*)d_in[4];
    const float* Wo = (const float*)d_in[5];

    float* F0 = (float*)d_out;
    float* F1 = F0 + MMDD;

    ushort_t* Fb  = (ushort_t*)d_ws;              // bf16 [f0;f1]  4 MB
    ushort_t* Qb  = Fb  + 2 * MMDD;               // 4 MB
    ushort_t* Khb = Qb  + 2 * MMDD;               // 4 MB K tile image
    ushort_t* Vhb = Khb + 2 * MMDD;               // 4 MB V tile image (permuted)
    ushort_t* Wb  = Vhb + 2 * MMDD;               // 4 MB bf16 weights
    ushort_t* Opb = Wb  + 2 * MMDD;               // 16 MB bf16 partials
    float*    Lpw = (float*)(Opb + 8 * MMDD);     // 1 MB fp32 partial sums l
    float*    tab = Lpw + 262144;                 // 2 MB rope table

    ushort_t* Wqb = Wb;
    ushort_t* Wkb = Wb + (size_t)NLAYERS * 65536;
    ushort_t* Wvb = Wb + (size_t)2 * NLAYERS * 65536;
    ushort_t* Wob = Wb + (size_t)3 * NLAYERS * 65536;

    setup<<<3072, 256, 0, stream>>>(f0_in, f1_in, Wq, Wk, Wv, Wo, F0, Fb, Wb, tab);

    for (int i = 0; i < NLAYERS; i++) {
        const ushort_t* wq = Wqb + (size_t)i * 65536;
        const ushort_t* wk = Wkb + (size_t)i * 65536;
        const ushort_t* wv = Wvb + (size_t)i * 65536;
        const ushort_t* wo = Wob + (size_t)i * 65536;

        if ((i & 1) == 0) {
            // self: both streams batched (M=8192); SPLIT=4 -> 2048 blocks (8/CU)
            selfQKV<<<1024, 256, 0, stream>>>(Fb, wq, wk, wv, Qb, Khb, Vhb, tab);
            attn11<4><<<2048, 256, 0, stream>>>(Qb, Khb, Vhb, Opb, Lpw, MM * 2);
            gemmO<4, 128><<<512, 256, 0, stream>>>(Opb, Lpw, wo, F0, F0, Fb, MM * 2);
        } else {
            // cross: Q(both) + KV(s=0 from f1) fused; then sequential passes
            crossQKV0<<<1024, 256, 0, stream>>>(Fb, wq, Fb + MMDD, wk, wv,
                                                Qb, Khb, Vhb);
            // s = 0: f0 attends f1
            attn11<8><<<2048, 256, 0, stream>>>(Qb, Khb, Vhb, Opb, Lpw, MM);
            gemmO<8, 64><<<256, 256, 0, stream>>>(Opb, Lpw, wo, F0, F0, Fb, MM);
            // s = 1: f1 attends UPDATED f0
            gemmKV<<<512, 256, 0, stream>>>(Fb, wk, wv, Khb, Vhb);
            attn11<8><<<2048, 256, 0, stream>>>(Qb + MMDD, Khb, Vhb, Opb, Lpw, MM);
            gemmO<8, 64><<<256, 256, 0, stream>>>(Opb, Lpw, wo, F1, F1,
                                                  Fb + MMDD, MM);
        }
    }
}

// Round 14
// 483.310 us; speedup vs baseline: 1.9108x; 1.9108x over previous
//
#include <hip/hip_runtime.h>

#define BB   2
#define LL   2048
#define DD   256
#define NH   8
#define MM   (BB*LL)
#define NLAYERS 8
#define MMDD ((size_t)MM*DD)

typedef unsigned short ushort_t;
typedef __attribute__((ext_vector_type(8))) short  short8;
typedef __attribute__((ext_vector_type(4))) float  f32x4;
typedef __attribute__((ext_vector_type(4))) unsigned int u32x4;
typedef __attribute__((ext_vector_type(2))) unsigned int u32x2;

#define CSC 0.2550500394f   /* 32^-0.5 * log2(e), folded into Q */

#define WAITV0 asm volatile("s_waitcnt vmcnt(0)" ::: "memory")
#define WAITV2 asm volatile("s_waitcnt vmcnt(2)" ::: "memory")
#define WAITV4 asm volatile("s_waitcnt vmcnt(4)" ::: "memory")
#define WAITV6 asm volatile("s_waitcnt vmcnt(6)" ::: "memory")
#define WAITLG asm volatile("s_waitcnt lgkmcnt(0)" ::: "memory")
#define BAR()  __builtin_amdgcn_s_barrier()
#define SCHED0 __builtin_amdgcn_sched_barrier(0)

__device__ __forceinline__ f32x4 mfma16(short8 a, short8 b, f32x4 c) {
    return __builtin_amdgcn_mfma_f32_16x16x32_bf16(a, b, c, 0, 0, 0);
}
__device__ __forceinline__ unsigned cvtpk(float lo, float hi) {
    unsigned r;
    asm volatile("v_cvt_pk_bf16_f32 %0, %1, %2" : "=v"(r) : "v"(lo), "v"(hi));
    return r;
}
__device__ __forceinline__ void pl32(unsigned &a, unsigned &b) {
    asm volatile("v_permlane32_swap_b32 %0, %1" : "+v"(a), "+v"(b));
}
__device__ __forceinline__ float bf2f(unsigned short h) {
    return __builtin_bit_cast(float, ((unsigned)h) << 16);
}
__device__ __forceinline__ void gll16(const void* gsrc, void* ldst) {
    __builtin_amdgcn_global_load_lds(
        (const __attribute__((address_space(1))) unsigned int*)gsrc,
        (__attribute__((address_space(3))) unsigned int*)ldst, 16, 0, 0);
}

// K tile image (per zh, per 64-key tile t): off = t*2048 + (dh>>3)*512 + kk*8 + (dh&7)
// V tile image: off = t*2048 + dh*64 + (c ^ (dh&7))*8 + u; chunk c holds permuted
//   keys pk(c&3, e) = 16((c&3)>>1)+4((c&3)&1)+8(e>>2)+(e&3); key = 32(c>>2)+pk.

// ---------------------------------------------------------------------------
// Fused setup: F/Fb init (0-1023), weight conv (1024-2047), rope table (2048+)
// ---------------------------------------------------------------------------
__global__ __launch_bounds__(256) void setup(const float* __restrict__ f0,
                                             const float* __restrict__ f1,
                                             const float* __restrict__ Wq,
                                             const float* __restrict__ Wk,
                                             const float* __restrict__ Wv,
                                             const float* __restrict__ Wo,
                                             float* __restrict__ F,
                                             ushort_t* __restrict__ Fb,
                                             ushort_t* __restrict__ Wb,
                                             float* __restrict__ tab) {
    int b = blockIdx.x, t = threadIdx.x;
    if (b < 1024) {
        int i = b * 256 + t;
        const float* src = (i < 131072) ? f0 : f1;
        int loc = i & 131071;
        const f32x4* p = (const f32x4*)(src + (size_t)loc * 8);
        f32x4 a = p[0], bb = p[1];
        *(f32x4*)&F[(size_t)i * 8]     = a;
        *(f32x4*)&F[(size_t)i * 8 + 4] = bb;
        u32x4 o = {cvtpk(a.x, a.y), cvtpk(a.z, a.w), cvtpk(bb.x, bb.y), cvtpk(bb.z, bb.w)};
        *(u32x4*)&Fb[(size_t)i * 8] = o;
    } else if (b < 2048) {
        int i = (b - 1024) * 256 + t;
        int reg = i >> 16, loc = i & 65535;
        const float* src = reg == 0 ? Wq : reg == 1 ? Wk : reg == 2 ? Wv : Wo;
        const f32x4* p = (const f32x4*)(src + (size_t)loc * 8);
        f32x4 x = p[0], y = p[1];
        u32x4 o = {cvtpk(x.x, x.y), cvtpk(x.z, x.w), cvtpk(y.x, y.y), cvtpk(y.z, y.w)};
        *(u32x4*)&Wb[(size_t)reg * 524288 + (size_t)loc * 8] = o;
    } else {
        int idx = (b - 2048) * 256 + t;
        int p = idx >> 7, j = idx & 127;
        float inv = __expf(-((float)j / 128.f) * 9.210340371976184f);
        float s, c;
        sincosf((float)p * inv, &s, &c);
        tab[(size_t)p * 256 + j]       = c;
        tab[(size_t)p * 256 + 128 + j] = s;
    }
}

// ---------------------------------------------------------------------------
// gemmQK body: self Q/K projection with fused RoPE (shared LDS arena:
// X 2x4096 @0, WL 2x4096 @8192, WH 2x4096 @16384).
// ---------------------------------------------------------------------------
__device__ __forceinline__ void gemmQK_body(int f, ushort_t* lds,
                                            const ushort_t* __restrict__ X,
                                            const ushort_t* __restrict__ WQ,
                                            const ushort_t* __restrict__ WK,
                                            ushort_t* __restrict__ DQ,
                                            ushort_t* __restrict__ KT,
                                            const float* __restrict__ tab) {
    const int tid = threadIdx.x, ln = tid & 63, w = tid >> 6;
    const int xcd = f & 7, u = f >> 3;
    const int bx = u & 3, byg = u >> 2;
    const int mat = bx >> 1, cg = bx & 1;
    const int by = xcd * 16 + byg;
    const int m0 = by * 64, n0 = cg * 64;
    const ushort_t* W = mat ? WK : WQ;

    auto stage = [&](int c, int buf) {
#pragma unroll
        for (int i = 0; i < 2; i++) {
            int sl = (w * 2 + i) * 64 + ln;
            int r = sl >> 3, x = sl & 7;
            int col = c * 64 + ((x ^ (r & 7)) << 3);
            gll16(X + (size_t)(m0 + r) * 256 + col,       &lds[buf * 4096 + (w * 2 + i) * 512]);
            gll16(W + (size_t)(n0 + r) * 256 + col,       &lds[8192 + buf * 4096 + (w * 2 + i) * 512]);
            gll16(W + (size_t)(n0 + 128 + r) * 256 + col, &lds[16384 + buf * 4096 + (w * 2 + i) * 512]);
        }
    };

    const int ql = ln & 15, gq = ln >> 4;
    const int wm = w >> 1, wn = w & 1;
    f32x4 z4 = {0.f, 0.f, 0.f, 0.f};
    f32x4 accL[2][2] = {{z4, z4}, {z4, z4}};
    f32x4 accH[2][2] = {{z4, z4}, {z4, z4}};

    stage(0, 0);
    stage(1, 1);
#pragma unroll
    for (int c = 0; c < 4; c++) {
        if (c < 3) { WAITV6; } else { WAITV0; }
        BAR(); SCHED0;
        const ushort_t* XL = &lds[(c & 1) * 4096];
        const ushort_t* WL = &lds[8192 + (c & 1) * 4096];
        const ushort_t* WH = &lds[16384 + (c & 1) * 4096];
        __builtin_amdgcn_s_setprio(1);
#pragma unroll
        for (int ks = 0; ks < 2; ks++) {
            int cc = ks * 4 + gq;
            int r0 = 32 * wm + ql, r1 = r0 + 16;
            int nr0 = 32 * wn + ql, nr1 = nr0 + 16;
            short8 a0 = *(const short8*)&XL[(r0 * 8 + (cc ^ (r0 & 7))) * 8];
            short8 a1 = *(const short8*)&XL[(r1 * 8 + (cc ^ (r1 & 7))) * 8];
            short8 l0 = *(const short8*)&WL[(nr0 * 8 + (cc ^ (nr0 & 7))) * 8];
            short8 l1 = *(const short8*)&WL[(nr1 * 8 + (cc ^ (nr1 & 7))) * 8];
            short8 h0 = *(const short8*)&WH[(nr0 * 8 + (cc ^ (nr0 & 7))) * 8];
            short8 h1 = *(const short8*)&WH[(nr1 * 8 + (cc ^ (nr1 & 7))) * 8];
            accL[0][0] = mfma16(a0, l0, accL[0][0]);
            accL[0][1] = mfma16(a0, l1, accL[0][1]);
            accL[1][0] = mfma16(a1, l0, accL[1][0]);
            accL[1][1] = mfma16(a1, l1, accL[1][1]);
            accH[0][0] = mfma16(a0, h0, accH[0][0]);
            accH[0][1] = mfma16(a0, h1, accH[0][1]);
            accH[1][0] = mfma16(a1, h0, accH[1][0]);
            accH[1][1] = mfma16(a1, h1, accH[1][1]);
        }
        __builtin_amdgcn_s_setprio(0);
        BAR();
        if (c + 2 < 4) stage(c + 2, c & 1);
    }

#pragma unroll
    for (int mf = 0; mf < 2; mf++)
#pragma unroll
        for (int nf = 0; nf < 2; nf++)
#pragma unroll
            for (int r = 0; r < 4; r++) {
                int mg = m0 + 32 * wm + 16 * mf + gq * 4 + r;
                int jl = n0 + 32 * wn + 16 * nf + ql;
                int pos = mg & (LL - 1);
                float a = accL[mf][nf][r], b = accH[mf][nf][r];
                float c = tab[(size_t)pos * 256 + jl];
                float s = tab[(size_t)pos * 256 + 128 + jl];
                float o1 = a * c - b * s;
                float o2 = b * c + a * s;
                if (mat == 0) {
                    o1 *= CSC; o2 *= CSC;
                    DQ[(size_t)mg * 256 + jl]       = (ushort_t)cvtpk(o1, o1);
                    DQ[(size_t)mg * 256 + jl + 128] = (ushort_t)cvtpk(o2, o2);
                } else {
                    int z = mg >> 11, key = mg & 2047;
                    int tt = key >> 6, kk = key & 63;
                    int dh = jl & 31, hA = jl >> 5;
                    size_t base = (size_t)tt * 2048 + (size_t)(dh >> 3) * 512
                                + (size_t)kk * 8 + (dh & 7);
                    KT[(size_t)(z * 8 + hA) * 65536 + base]     = (ushort_t)cvtpk(o1, o1);
                    KT[(size_t)(z * 8 + hA + 4) * 65536 + base] = (ushort_t)cvtpk(o2, o2);
                }
            }
}

// ---------------------------------------------------------------------------
// gemm5 body (3-buffer pipelined; shared LDS arena: X 3x4096 @0, W @12288).
// modes: 2 bf16 row | 3 V tile image | 4 bf16*CSC row | 5 K tile
// ---------------------------------------------------------------------------
template<int NQ, int NK, int NV, int QMODE, int KMODE, int NTY>
__device__ __forceinline__ void gemm5_body(int f, ushort_t* lds,
                                           const ushort_t* __restrict__ X,
                                           const ushort_t* __restrict__ WQ,
                                           const ushort_t* __restrict__ WK,
                                           const ushort_t* __restrict__ WV,
                                           ushort_t* __restrict__ DQ,
                                           ushort_t* __restrict__ DK,
                                           ushort_t* __restrict__ DVT) {
    constexpr int NTX = NQ + NK + NV;
    const int tid = threadIdx.x, ln = tid & 63, w = tid >> 6;
    const int xcd = f & 7, s = f >> 3;
    const int bx = s % NTX, byg = s / NTX;
    const int by = xcd * (NTY / 8) + byg;
    const int m0 = by * 64;

    const ushort_t* W; ushort_t* DH; int n0, mode;
    if (NQ && bx < NQ)           { W = WQ; DH = DQ;  mode = QMODE; n0 = bx * 64; }
    else if (NK && bx < NQ + NK) { W = WK; DH = DK;  mode = KMODE; n0 = (bx - NQ) * 64; }
    else                         { W = WV; DH = DVT; mode = 3; n0 = (bx - NQ - NK) * 64; }

    auto stage = [&](int c, int buf) {
#pragma unroll
        for (int i = 0; i < 2; i++) {
            int sl = (w * 2 + i) * 64 + ln;
            int r = sl >> 3, x = sl & 7;
            int col = c * 64 + ((x ^ (r & 7)) << 3);
            gll16(X + (size_t)(m0 + r) * 256 + col, &lds[buf * 4096 + (w * 2 + i) * 512]);
            gll16(W + (size_t)(n0 + r) * 256 + col, &lds[12288 + buf * 4096 + (w * 2 + i) * 512]);
        }
    };

    const int ql = ln & 15, gq = ln >> 4;
    const int wm = w >> 1, wn = w & 1;
    f32x4 z4 = {0.f, 0.f, 0.f, 0.f};
    f32x4 acc[2][2] = {{z4, z4}, {z4, z4}};

    stage(0, 0);
    stage(1, 1);
#pragma unroll
    for (int c = 0; c < 4; c++) {
        if (c < 3) { WAITV4; } else { WAITV0; }
        BAR(); SCHED0;
        if (c + 2 < 4) stage(c + 2, (c + 2) % 3);
        const ushort_t* XL = &lds[(c % 3) * 4096];
        const ushort_t* WL = &lds[12288 + (c % 3) * 4096];
        __builtin_amdgcn_s_setprio(1);
#pragma unroll
        for (int ks = 0; ks < 2; ks++) {
            int cc = ks * 4 + gq;
            int r0 = 32 * wm + ql, r1 = r0 + 16;
            int nr0 = 32 * wn + ql, nr1 = nr0 + 16;
            short8 a0 = *(const short8*)&XL[(r0 * 8 + (cc ^ (r0 & 7))) * 8];
            short8 a1 = *(const short8*)&XL[(r1 * 8 + (cc ^ (r1 & 7))) * 8];
            short8 b0 = *(const short8*)&WL[(nr0 * 8 + (cc ^ (nr0 & 7))) * 8];
            short8 b1 = *(const short8*)&WL[(nr1 * 8 + (cc ^ (nr1 & 7))) * 8];
            acc[0][0] = mfma16(a0, b0, acc[0][0]);
            acc[0][1] = mfma16(a0, b1, acc[0][1]);
            acc[1][0] = mfma16(a1, b0, acc[1][0]);
            acc[1][1] = mfma16(a1, b1, acc[1][1]);
        }
        __builtin_amdgcn_s_setprio(0);
    }

    if (mode == 3) {
        float* scr = (float*)lds;
        __syncthreads();
#pragma unroll
        for (int mf = 0; mf < 2; mf++)
#pragma unroll
            for (int nf = 0; nf < 2; nf++)
#pragma unroll
                for (int r = 0; r < 4; r++) {
                    int nloc = 32 * wn + 16 * nf + ql;
                    int mloc = 32 * wm + 16 * mf + 4 * gq + r;
                    scr[nloc * 65 + mloc] = acc[mf][nf][r];
                }
        __syncthreads();
        int nloc = tid >> 2, mc = (tid & 3) * 16;
        int ng = n0 + nloc, hh = ng >> 5, dh = ng & 31;
        int mg = m0 + mc;
        int z = mg >> 11, key = mg & 2047;
        int tt = key >> 6;
        int ks = (mc >> 5) & 1, J = (mc >> 4) & 1;
        int cA = 4 * ks + 2 * J, cB = cA + 1;
        int swz = dh & 7;
        const float* sc = &scr[nloc * 65 + mc];
        u32x2 q0 = {cvtpk(sc[0], sc[1]),   cvtpk(sc[2], sc[3])};
        u32x2 q1 = {cvtpk(sc[4], sc[5]),   cvtpk(sc[6], sc[7])};
        u32x2 q2 = {cvtpk(sc[8], sc[9]),   cvtpk(sc[10], sc[11])};
        u32x2 q3 = {cvtpk(sc[12], sc[13]), cvtpk(sc[14], sc[15])};
        ushort_t* base = &DVT[(size_t)(z * 8 + hh) * 65536 + (size_t)tt * 2048 + dh * 64];
        *(u32x2*)&base[(cA ^ swz) * 8]     = q0;
        *(u32x2*)&base[(cB ^ swz) * 8]     = q1;
        *(u32x2*)&base[(cA ^ swz) * 8 + 4] = q2;
        *(u32x2*)&base[(cB ^ swz) * 8 + 4] = q3;
    } else {
#pragma unroll
        for (int mf = 0; mf < 2; mf++)
#pragma unroll
            for (int nf = 0; nf < 2; nf++)
#pragma unroll
                for (int r = 0; r < 4; r++) {
                    int mg = m0 + 32 * wm + 16 * mf + gq * 4 + r;
                    int ng = n0 + 32 * wn + 16 * nf + ql;
                    float v = acc[mf][nf][r];
                    if (mode == 2) {
                        DH[(size_t)mg * 256 + ng] = (ushort_t)cvtpk(v, v);
                    } else if (mode == 5) {
                        int zh = (mg >> 11) * 8 + (ng >> 5);
                        size_t off = (size_t)zh * 65536
                                   + (size_t)((mg & 2047) >> 6) * 2048
                                   + (size_t)((ng & 31) >> 3) * 512
                                   + (size_t)(mg & 63) * 8 + (ng & 7);
                        DH[off] = (ushort_t)cvtpk(v, v);
                    } else {
                        float vs = v * CSC;
                        DH[(size_t)mg * 256 + ng] = (ushort_t)cvtpk(vs, vs);
                    }
                }
    }
}

// ---------------------------------------------------------------------------
// Fused dispatches
// ---------------------------------------------------------------------------
__global__ __launch_bounds__(256) void selfQKV(const ushort_t* __restrict__ Fb,
                                               const ushort_t* __restrict__ wq,
                                               const ushort_t* __restrict__ wk,
                                               const ushort_t* __restrict__ wv,
                                               ushort_t* __restrict__ Qb,
                                               ushort_t* __restrict__ Khb,
                                               ushort_t* __restrict__ Vhb,
                                               const float* __restrict__ tab) {
    __shared__ ushort_t lds[24576];
    int f = blockIdx.x;
    if (f < 512)
        gemmQK_body(f, lds, Fb, wq, wk, Qb, Khb, tab);
    else
        gemm5_body<0, 0, 4, 0, 0, 128>(f - 512, lds, Fb, nullptr, nullptr, wv,
                                       nullptr, nullptr, Vhb);
}

__global__ __launch_bounds__(256) void crossQKV0(const ushort_t* __restrict__ Fb,
                                                 const ushort_t* __restrict__ wq,
                                                 const ushort_t* __restrict__ sb,
                                                 const ushort_t* __restrict__ wk,
                                                 const ushort_t* __restrict__ wv,
                                                 ushort_t* __restrict__ Qb,
                                                 ushort_t* __restrict__ Khb,
                                                 ushort_t* __restrict__ Vhb) {
    __shared__ ushort_t lds[24576];
    int f = blockIdx.x;
    if (f < 512)
        gemm5_body<4, 0, 0, 4, 0, 128>(f, lds, Fb, wq, nullptr, nullptr,
                                       Qb, nullptr, nullptr);
    else
        gemm5_body<0, 4, 4, 0, 5, 64>(f - 512, lds, sb, nullptr, wk, wv,
                                      nullptr, Khb, Vhb);
}

__global__ __launch_bounds__(256) void gemmKV(const ushort_t* __restrict__ sb,
                                              const ushort_t* __restrict__ wk,
                                              const ushort_t* __restrict__ wv,
                                              ushort_t* __restrict__ Khb,
                                              ushort_t* __restrict__ Vhb) {
    __shared__ ushort_t lds[24576];
    gemm5_body<0, 4, 4, 0, 5, 64>(blockIdx.x, lds, sb, nullptr, wk, wv,
                                  nullptr, Khb, Vhb);
}

// ---------------------------------------------------------------------------
// Out-projection GEMM with fused split-combine; bf16 partials.
// ---------------------------------------------------------------------------
template<int SPLIT, int NTY>
__global__ __launch_bounds__(256) void gemmO(const ushort_t* __restrict__ Opb,
                                             const float* __restrict__ Lp,
                                             const ushort_t* __restrict__ W,
                                             const float* __restrict__ Res,
                                             float* __restrict__ OutF,
                                             ushort_t* __restrict__ OutH,
                                             int mrows) {
    __shared__ ushort_t Xf[64 * 256];
    __shared__ ushort_t Wpb[3][4096];
    const int tid = threadIdx.x, ln = tid & 63, w = tid >> 6;
    const int f = blockIdx.x;
    const int xcd = f & 7, s = f >> 3;
    const int bx = s & 3, byg = s >> 2;
    const int by = xcd * (NTY / 8) + byg;
    const int m0 = by * 64, n0 = bx * 64;

    auto stageW = [&](int c, int buf) {
#pragma unroll
        for (int i = 0; i < 2; i++) {
            int sl = (w * 2 + i) * 64 + ln;
            int r = sl >> 3, x = sl & 7;
            int col = c * 64 + ((x ^ (r & 7)) << 3);
            gll16(W + (size_t)(n0 + r) * 256 + col, &Wpb[buf][(w * 2 + i) * 512]);
        }
    };
    stageW(0, 0);
    stageW(1, 1);

    const int xr = tid >> 2, q = tid & 3, hb = q >> 1;
    float inv[4];
#pragma unroll
    for (int hh = 0; hh < 4; hh++) {
        float l = 0.f;
#pragma unroll
        for (int sp = 0; sp < SPLIT; sp++)
            l += Lp[(size_t)sp * mrows * 8 + (size_t)(m0 + xr) * 8 + 2 * hh + hb];
        inv[hh] = 1.f / l;
    }
#pragma unroll
    for (int p = 0; p < 4; p++) {
        int col = q * 16 + 64 * p;
        f32x4 a0 = {0.f,0.f,0.f,0.f}, a1 = a0, a2 = a0, a3 = a0;
#pragma unroll
        for (int sp = 0; sp < SPLIT; sp++) {
            const ushort_t* src = &Opb[((size_t)sp * mrows + m0 + xr) * 256 + col];
            u32x4 v0 = *(const u32x4*)&src[0];
            u32x4 v1 = *(const u32x4*)&src[8];
            f32x4 b0 = {bf2f(v0.x & 0xffff), bf2f(v0.x >> 16),
                        bf2f(v0.y & 0xffff), bf2f(v0.y >> 16)};
            f32x4 b1 = {bf2f(v0.z & 0xffff), bf2f(v0.z >> 16),
                        bf2f(v0.w & 0xffff), bf2f(v0.w >> 16)};
            f32x4 b2 = {bf2f(v1.x & 0xffff), bf2f(v1.x >> 16),
                        bf2f(v1.y & 0xffff), bf2f(v1.y >> 16)};
            f32x4 b3 = {bf2f(v1.z & 0xffff), bf2f(v1.z >> 16),
                        bf2f(v1.w & 0xffff), bf2f(v1.w >> 16)};
            a0 += b0; a1 += b1; a2 += b2; a3 += b3;
        }
        float iv = inv[p];
        a0 *= iv; a1 *= iv; a2 *= iv; a3 *= iv;
        u32x4 w0 = {cvtpk(a0.x, a0.y), cvtpk(a0.z, a0.w),
                    cvtpk(a1.x, a1.y), cvtpk(a1.z, a1.w)};
        u32x4 w1 = {cvtpk(a2.x, a2.y), cvtpk(a2.z, a2.w),
                    cvtpk(a3.x, a3.y), cvtpk(a3.z, a3.w)};
        int xc0 = q * 2;
        *(u32x4*)&Xf[xr * 256 + p * 64 + ((xc0)     ^ (xr & 7)) * 8] = w0;
        *(u32x4*)&Xf[xr * 256 + p * 64 + ((xc0 + 1) ^ (xr & 7)) * 8] = w1;
    }
    WAITLG;
    BAR(); SCHED0;

    const int ql = ln & 15, gq = ln >> 4;
    const int wm = w >> 1, wn = w & 1;
    f32x4 z4 = {0.f, 0.f, 0.f, 0.f};
    f32x4 acc[2][2] = {{z4, z4}, {z4, z4}};
#pragma unroll
    for (int c = 0; c < 4; c++) {
        if (c < 3) { WAITV2; } else { WAITV0; }
        BAR(); SCHED0;
        if (c + 2 < 4) stageW(c + 2, (c + 2) % 3);
        const ushort_t* WL = Wpb[c % 3];
        __builtin_amdgcn_s_setprio(1);
#pragma unroll
        for (int ks = 0; ks < 2; ks++) {
            int cc = ks * 4 + gq;
            int r0 = 32 * wm + ql, r1 = r0 + 16;
            int nr0 = 32 * wn + ql, nr1 = nr0 + 16;
            short8 a0 = *(const short8*)&Xf[r0 * 256 + c * 64 + (cc ^ (r0 & 7)) * 8];
            short8 a1 = *(const short8*)&Xf[r1 * 256 + c * 64 + (cc ^ (r1 & 7)) * 8];
            short8 b0 = *(const short8*)&WL[(nr0 * 8 + (cc ^ (nr0 & 7))) * 8];
            short8 b1 = *(const short8*)&WL[(nr1 * 8 + (cc ^ (nr1 & 7))) * 8];
            acc[0][0] = mfma16(a0, b0, acc[0][0]);
            acc[0][1] = mfma16(a0, b1, acc[0][1]);
            acc[1][0] = mfma16(a1, b0, acc[1][0]);
            acc[1][1] = mfma16(a1, b1, acc[1][1]);
        }
        __builtin_amdgcn_s_setprio(0);
    }

#pragma unroll
    for (int mf = 0; mf < 2; mf++)
#pragma unroll
        for (int nf = 0; nf < 2; nf++)
#pragma unroll
            for (int r = 0; r < 4; r++) {
                int mg = m0 + 32 * wm + 16 * mf + gq * 4 + r;
                int ng = n0 + 32 * wn + 16 * nf + ql;
                size_t idx = (size_t)mg * 256 + ng;
                float o = Res[idx] + acc[mf][nf][r];
                OutF[idx] = o;
                OutH[idx] = (ushort_t)cvtpk(o, o);
            }
}

// ---------------------------------------------------------------------------
// Flash MFMA attention v10 (round-12 proven): 3-buffer 64-key tiles, counted
// vmcnt(2), 1 barrier/tile, in-register P via permlane32, ones-MFMA row-sum,
// 24KB LDS, __launch_bounds__(256,6) -> 6 blocks/CU. bf16 partials.
// grid = 8 xcd * 16 qb * (zcnt*SPLIT); unequal splits via t0/NT arithmetic.
// ---------------------------------------------------------------------------
template<int SPLIT>
__global__ __launch_bounds__(256, 6) void attn10(const ushort_t* __restrict__ Q,
                                                 const ushort_t* __restrict__ K,
                                                 const ushort_t* __restrict__ Vt,
                                                 ushort_t* __restrict__ Opb,
                                                 float* __restrict__ Lp, int mrows) {
    __shared__ ushort_t K_lds[3][2048];
    __shared__ ushort_t V_lds[3][2048];

    const int tid = threadIdx.x, ln = tid & 63, w = tid >> 6;
    const int ql = ln & 15, gq = ln >> 4;
    const int f = blockIdx.x;
    const int xcd = f & 7, slot = f >> 3;
    const int qb = slot & 15, gg = slot >> 4;
    const int h = xcd;
    const int zz = gg / SPLIT, sp = gg % SPLIT;
    const int t0 = (sp * 32) / SPLIT;
    const int NT = ((sp + 1) * 32) / SPLIT - t0;
    const int q0 = qb * 128 + w * 32;
    const size_t rb = (size_t)zz * 2048;
    const int zh = zz * 8 + h;

    short8 qfA = *(const short8*)&Q[(rb + q0 + ql) * 256 + h * 32 + gq * 8];
    short8 qfB = *(const short8*)&Q[(rb + q0 + 16 + ql) * 256 + h * 32 + gq * 8];

    const ushort_t* kt = K  + (size_t)zh * 65536 + (size_t)t0 * 2048 + tid * 8;
    const ushort_t* vt = Vt + (size_t)zh * 65536 + (size_t)t0 * 2048 + tid * 8;

    gll16(kt,        &K_lds[0][w * 512]);
    gll16(vt,        &V_lds[0][w * 512]);
    gll16(kt + 2048, &K_lds[1][w * 512]);
    gll16(vt + 2048, &V_lds[1][w * 512]);

    const short os = (short)0x3F80;             // bf16 1.0
    const short8 ones = {os, os, os, os, os, os, os, os};
    f32x4 z4 = {0.f, 0.f, 0.f, 0.f};
    f32x4 o0A = z4, o1A = z4, o0B = z4, o1B = z4, laccA = z4, laccB = z4;

    int cur = 0, pre = 2;
    for (int t = 0; t < NT; t++) {
        if (t < NT - 1) { WAITV2; } else { WAITV0; }
        BAR(); SCHED0;
        if (t + 2 < NT) {
            gll16(kt + (size_t)(t + 2) * 2048, &K_lds[pre][w * 512]);
            gll16(vt + (size_t)(t + 2) * 2048, &V_lds[pre][w * 512]);
        }
        const ushort_t* KL = K_lds[cur];
        const ushort_t* VL = V_lds[cur];

        f32x4 stA[4], stB[4];
        __builtin_amdgcn_s_setprio(1);
#pragma unroll
        for (int j = 0; j < 4; j++) {
            short8 kf = *(const short8*)&KL[(gq * 64 + 16 * j + ql) * 8];
            stA[j] = mfma16(kf, qfA, z4);
            stB[j] = mfma16(kf, qfB, z4);
        }
        __builtin_amdgcn_s_setprio(0);
#pragma unroll
        for (int j = 0; j < 4; j++)
#pragma unroll
            for (int r = 0; r < 4; r++) {
                stA[j][r] = __builtin_amdgcn_exp2f(stA[j][r]);
                stB[j][r] = __builtin_amdgcn_exp2f(stB[j][r]);
            }
        unsigned aLo[4], aHi[4], bLo[4], bHi[4];
#pragma unroll
        for (int j = 0; j < 4; j++) {
            aLo[j] = cvtpk(stA[j][0], stA[j][1]);
            aHi[j] = cvtpk(stA[j][2], stA[j][3]);
            bLo[j] = cvtpk(stB[j][0], stB[j][1]);
            bHi[j] = cvtpk(stB[j][2], stB[j][3]);
        }
        pl32(aLo[0], aLo[1]); pl32(aHi[0], aHi[1]);
        pl32(aLo[2], aLo[3]); pl32(aHi[2], aHi[3]);
        pl32(bLo[0], bLo[1]); pl32(bHi[0], bHi[1]);
        pl32(bLo[2], bLo[3]); pl32(bHi[2], bHi[3]);
        u32x4 fA0 = {aLo[0], aHi[0], aLo[1], aHi[1]};
        u32x4 fA1 = {aLo[2], aHi[2], aLo[3], aHi[3]};
        u32x4 fB0 = {bLo[0], bHi[0], bLo[1], bHi[1]};
        u32x4 fB1 = {bLo[2], bHi[2], bLo[3], bHi[3]};
        short8 pfA0 = __builtin_bit_cast(short8, fA0);
        short8 pfA1 = __builtin_bit_cast(short8, fA1);
        short8 pfB0 = __builtin_bit_cast(short8, fB0);
        short8 pfB1 = __builtin_bit_cast(short8, fB1);

        __builtin_amdgcn_s_setprio(1);
#pragma unroll
        for (int ks = 0; ks < 2; ks++) {
            int sw = (4 * ks + gq) ^ (ql & 7);
            short8 vf0 = *(const short8*)&VL[(ql * 8 + sw) * 8];
            short8 vf1 = *(const short8*)&VL[((16 + ql) * 8 + sw) * 8];
            short8 pA = ks ? pfA1 : pfA0;
            short8 pB = ks ? pfB1 : pfB0;
            o0A = mfma16(vf0, pA, o0A);
            o1A = mfma16(vf1, pA, o1A);
            o0B = mfma16(vf0, pB, o0B);
            o1B = mfma16(vf1, pB, o1B);
            laccA = mfma16(ones, pA, laccA);
            laccB = mfma16(ones, pB, laccB);
        }
        __builtin_amdgcn_s_setprio(0);
        cur = (cur == 2) ? 0 : cur + 1;
        pre = (pre == 2) ? 0 : pre + 1;
    }

    size_t rowA = rb + q0 + ql, rowB = rowA + 16;
    ushort_t* obA = Opb + ((size_t)sp * mrows + rowA) * 256 + h * 32;
    ushort_t* obB = Opb + ((size_t)sp * mrows + rowB) * 256 + h * 32;
    u32x2 wA0 = {cvtpk(o0A.x, o0A.y), cvtpk(o0A.z, o0A.w)};
    u32x2 wA1 = {cvtpk(o1A.x, o1A.y), cvtpk(o1A.z, o1A.w)};
    u32x2 wB0 = {cvtpk(o0B.x, o0B.y), cvtpk(o0B.z, o0B.w)};
    u32x2 wB1 = {cvtpk(o1B.x, o1B.y), cvtpk(o1B.z, o1B.w)};
    *(u32x2*)&obA[gq * 4]      = wA0;
    *(u32x2*)&obA[16 + gq * 4] = wA1;
    *(u32x2*)&obB[gq * 4]      = wB0;
    *(u32x2*)&obB[16 + gq * 4] = wB1;
    if (gq == 0) {
        Lp[(size_t)sp * mrows * 8 + rowA * 8 + h] = laccA[0];
        Lp[(size_t)sp * mrows * 8 + rowB * 8 + h] = laccB[0];
    }
}

// ---------------------------------------------------------------------------
extern "C" void kernel_launch(void* const* d_in, const int* in_sizes, int n_in,
                              void* d_out, int out_size, void* d_ws, size_t ws_size,
                              hipStream_t stream) {
    const float* f0_in = (const float*)d_in[0];
    const float* f1_in = (const float*)d_in[1];
    const float* Wq = (const float*)d_in[2];
    const float* Wk = (const float*)d_in[3];
    const float* Wv = (const float*)d_in[4];
    const float* Wo = (const float*)d_in[5];

    float* F0 = (float*)d_out;
    float* F1 = F0 + MMDD;

    ushort_t* Fb  = (ushort_t*)d_ws;              // bf16 [f0;f1]  4 MB
    ushort_t* Qb  = Fb  + 2 * MMDD;               // 4 MB
    ushort_t* Khb = Qb  + 2 * MMDD;               // 4 MB K tile image
    ushort_t* Vhb = Khb + 2 * MMDD;               // 4 MB V tile image (permuted)
    ushort_t* Wb  = Vhb + 2 * MMDD;               // 4 MB bf16 weights
    ushort_t* Opb = Wb  + 2 * MMDD;               // 16 MB bf16 partials
    float*    Lpw = (float*)(Opb + 8 * MMDD);     // 1 MB fp32 partial sums l
    float*    tab = Lpw + 262144;                 // 2 MB rope table

    ushort_t* Wqb = Wb;
    ushort_t* Wkb = Wb + (size_t)NLAYERS * 65536;
    ushort_t* Wvb = Wb + (size_t)2 * NLAYERS * 65536;
    ushort_t* Wob = Wb + (size_t)3 * NLAYERS * 65536;

    setup<<<3072, 256, 0, stream>>>(f0_in, f1_in, Wq, Wk, Wv, Wo, F0, Fb, Wb, tab);

    for (int i = 0; i < NLAYERS; i++) {
        const ushort_t* wq = Wqb + (size_t)i * 65536;
        const ushort_t* wk = Wkb + (size_t)i * 65536;
        const ushort_t* wv = Wvb + (size_t)i * 65536;
        const ushort_t* wo = Wob + (size_t)i * 65536;

        if ((i & 1) == 0) {
            // self: both streams batched (M=8192); SPLIT=3 (10/11/11 tiles)
            selfQKV<<<1024, 256, 0, stream>>>(Fb, wq, wk, wv, Qb, Khb, Vhb, tab);
            attn10<3><<<1536, 256, 0, stream>>>(Qb, Khb, Vhb, Opb, Lpw, MM * 2);
            gemmO<3, 128><<<512, 256, 0, stream>>>(Opb, Lpw, wo, F0, F0, Fb, MM * 2);
        } else {
            // cross: Q(both) + KV(s=0 from f1) fused; then sequential passes
            crossQKV0<<<1024, 256, 0, stream>>>(Fb, wq, Fb + MMDD, wk, wv,
                                                Qb, Khb, Vhb);
            // s = 0: f0 attends f1
            attn10<8><<<2048, 256, 0, stream>>>(Qb, Khb, Vhb, Opb, Lpw, MM);
            gemmO<8, 64><<<256, 256, 0, stream>>>(Opb, Lpw, wo, F0, F0, Fb, MM);
            // s = 1: f1 attends UPDATED f0
            gemmKV<<<512, 256, 0, stream>>>(Fb, wk, wv, Khb, Vhb);
            attn10<8><<<2048, 256, 0, stream>>>(Qb + MMDD, Khb, Vhb, Opb, Lpw, MM);
            gemmO<8, 64><<<256, 256, 0, stream>>>(Opb, Lpw, wo, F1, F1,
                                                  Fb + MMDD, MM);
        }
    }
}